// Round 22
// baseline (330.193 us; speedup 1.0000x reference)
//
#include <hip/hip_runtime.h>
#include <hip/hip_fp16.h>

#define H    256
#define W    256
#define WH   129            // W/2 + 1
#define VLEN 182            // max radial bin + 1
#define NIMG 64             // 32 pred + 32 target
#define ZSTR 516            // zbuf row stride in floats

// Diagnostic repeat counts (idempotent; real per-kernel time = dur/REP)
#define REP_ROW 8
#define REP_COL 4
#define REP_FIN 16

typedef __attribute__((ext_vector_type(2))) unsigned uint2v;

__device__ __forceinline__ int isqrt_fast(int s2) {
    int r = (int)__builtin_amdgcn_sqrtf((float)s2);
    r -= (r * r > s2);
    r += ((r + 1) * (r + 1) <= s2);
    return r;
}

__device__ __forceinline__ float2 cmul(float2 a, float2 b) {
    return make_float2(a.x * b.x - a.y * b.y, a.x * b.y + a.y * b.x);
}

// Twiddle e^{-2*pi*i*frac} via raw v_sin/v_cos (argument in revolutions).
__device__ __forceinline__ float2 twid(float frac) {
    const float s = __builtin_amdgcn_sinf(frac);
    const float c = __builtin_amdgcn_cosf(frac);
    return make_float2(c, -s);
}

// 256-point DIF FFT held by one 64-lane wave; thread t owns positions
// i = t + 64r (r=0..3). On exit, position i holds X[bitrev8(i)].
__device__ __forceinline__ void wfft256(float2 z[4], int t) {
    // m=256
    {
        const float2 w0 = twid((float)t * (1.0f / 256.0f));
        const float2 w1 = make_float2(w0.y, -w0.x);    // w0 * (-i)
        float2 u0 = z[0], v0 = z[2], u1 = z[1], v1 = z[3];
        z[0] = make_float2(u0.x + v0.x, u0.y + v0.y);
        z[2] = cmul(make_float2(u0.x - v0.x, u0.y - v0.y), w0);
        z[1] = make_float2(u1.x + v1.x, u1.y + v1.y);
        z[3] = cmul(make_float2(u1.x - v1.x, u1.y - v1.y), w1);
    }
    // m=128
    {
        const float2 w = twid((float)t * (1.0f / 128.0f));
        float2 u0 = z[0], v0 = z[1], u1 = z[2], v1 = z[3];
        z[0] = make_float2(u0.x + v0.x, u0.y + v0.y);
        z[1] = cmul(make_float2(u0.x - v0.x, u0.y - v0.y), w);
        z[2] = make_float2(u1.x + v1.x, u1.y + v1.y);
        z[3] = cmul(make_float2(u1.x - v1.x, u1.y - v1.y), w);
    }
    // m=64: permlane32_swap
    {
        const float2 w = twid((float)(t & 31) * (1.0f / 64.0f));
        const bool hi = (t & 32) != 0;
        #pragma unroll
        for (int r = 0; r < 4; ++r) {
            const uint2v px = __builtin_amdgcn_permlane32_swap(
                __builtin_bit_cast(unsigned, z[r].x),
                __builtin_bit_cast(unsigned, z[r].x), false, false);
            const uint2v py = __builtin_amdgcn_permlane32_swap(
                __builtin_bit_cast(unsigned, z[r].y),
                __builtin_bit_cast(unsigned, z[r].y), false, false);
            const float ox = __builtin_bit_cast(float, hi ? px[0] : px[1]);
            const float oy = __builtin_bit_cast(float, hi ? py[0] : py[1]);
            if (hi) z[r] = cmul(make_float2(ox - z[r].x, oy - z[r].y), w);
            else    z[r] = make_float2(z[r].x + ox, z[r].y + oy);
        }
    }
    // m=32: permlane16_swap
    {
        const float2 w = twid((float)(t & 15) * (1.0f / 32.0f));
        const bool hi = (t & 16) != 0;
        #pragma unroll
        for (int r = 0; r < 4; ++r) {
            const uint2v px = __builtin_amdgcn_permlane16_swap(
                __builtin_bit_cast(unsigned, z[r].x),
                __builtin_bit_cast(unsigned, z[r].x), false, false);
            const uint2v py = __builtin_amdgcn_permlane16_swap(
                __builtin_bit_cast(unsigned, z[r].y),
                __builtin_bit_cast(unsigned, z[r].y), false, false);
            const float ox = __builtin_bit_cast(float, hi ? px[0] : px[1]);
            const float oy = __builtin_bit_cast(float, hi ? py[0] : py[1]);
            if (hi) z[r] = cmul(make_float2(ox - z[r].x, oy - z[r].y), w);
            else    z[r] = make_float2(z[r].x + ox, z[r].y + oy);
        }
    }
    // m=16
    {
        const float2 w = twid((float)(t & 7) * (1.0f / 16.0f));
        const bool hi = (t & 8) != 0;
        #pragma unroll
        for (int r = 0; r < 4; ++r) {
            float2 o;
            o.x = __shfl_xor(z[r].x, 8, 64);
            o.y = __shfl_xor(z[r].y, 8, 64);
            if (hi) z[r] = cmul(make_float2(o.x - z[r].x, o.y - z[r].y), w);
            else    z[r] = make_float2(z[r].x + o.x, z[r].y + o.y);
        }
    }
    // m=8
    {
        const float2 w = twid((float)(t & 3) * (1.0f / 8.0f));
        const bool hi = (t & 4) != 0;
        #pragma unroll
        for (int r = 0; r < 4; ++r) {
            float2 o;
            o.x = __shfl_xor(z[r].x, 4, 64);
            o.y = __shfl_xor(z[r].y, 4, 64);
            if (hi) z[r] = cmul(make_float2(o.x - z[r].x, o.y - z[r].y), w);
            else    z[r] = make_float2(z[r].x + o.x, z[r].y + o.y);
        }
    }
    // m=4
    {
        const bool hi  = (t & 2) != 0;
        const bool odd = (t & 1) != 0;
        #pragma unroll
        for (int r = 0; r < 4; ++r) {
            float2 o;
            o.x = __shfl_xor(z[r].x, 2, 64);
            o.y = __shfl_xor(z[r].y, 2, 64);
            float2 d = hi ? make_float2(o.x - z[r].x, o.y - z[r].y)
                          : make_float2(z[r].x + o.x, z[r].y + o.y);
            if (hi && odd) d = make_float2(d.y, -d.x);   // * (-i)
            z[r] = d;
        }
    }
    // m=2
    {
        const bool hi = (t & 1) != 0;
        #pragma unroll
        for (int r = 0; r < 4; ++r) {
            float2 o;
            o.x = __shfl_xor(z[r].x, 1, 64);
            o.y = __shfl_xor(z[r].y, 1, 64);
            z[r] = hi ? make_float2(o.x - z[r].x, o.y - z[r].y)
                      : make_float2(z[r].x + o.x, z[r].y + o.y);
        }
    }
}

// 8 waves/block, XCD-pinned (img = b & 63). DIAGNOSTIC: body repeated
// REP_ROW times (idempotent stores); memory clobber defeats hoisting.
__global__ __launch_bounds__(512)
void rowfft_wave(const float* __restrict__ pred, const float* __restrict__ targ,
                 uint2* __restrict__ GT /* [NIMG][WH][128] uint2 = row-pair */,
                 float* __restrict__ gsum /* [NIMG][VLEN] */,
                 float* __restrict__ out) {
    __shared__ float zbuf[8][ZSTR];
    const int tid  = threadIdx.x;
    const int t    = tid & 63;
    const int wid  = tid >> 6;
    const int b    = blockIdx.x;       // 0..1023
    const int img  = b & 63;           // XCD pin
    const int k16  = b >> 6;           // 0..15
    const int pair = (k16 << 3) | wid;
    const int rowA = pair * 2;

    if (k16 == 0) {
        if (tid < VLEN) gsum[img * VLEN + tid] = 0.0f;
    }
    if (b == 0 && tid == 0) out[0] = 0.0f;

    const float* src  = (img < 32) ? pred : targ;
    const float* base = src + (size_t)(img & 31) * (3 * H * W) + (size_t)rowA * W;

    for (int it = 0; it < REP_ROW; ++it) {
        asm volatile("" ::: "memory");   // force real reloads each iteration

        float2 z[4];
        #pragma unroll
        for (int r = 0; r < 4; ++r) {
            const int n = t + (r << 6);
            const float aR = __builtin_nontemporal_load(base + n);
            const float aG = __builtin_nontemporal_load(base + H * W + n);
            const float aB = __builtin_nontemporal_load(base + 2 * H * W + n);
            const float bR = __builtin_nontemporal_load(base + W + n);
            const float bG = __builtin_nontemporal_load(base + H * W + W + n);
            const float bB = __builtin_nontemporal_load(base + 2 * H * W + W + n);
            z[r] = make_float2(0.299f * aR + 0.587f * aG + 0.114f * aB,
                               0.299f * bR + 0.587f * bG + 0.114f * bB);
        }

        wfft256(z, t);

        float* zr = zbuf[wid];
        float* zi = zr + 256;
        #pragma unroll
        for (int r = 0; r < 4; ++r) {
            const int x  = (int)(__brev((unsigned)(t + (r << 6))) >> 24);
            const int sx = x ^ (x >> 5);
            zr[sx] = z[r].x; zi[sx] = z[r].y;
        }
        __syncthreads();

        uint2* dst = GT + (size_t)img * WH * 128;
        const int basePair = k16 << 3;
        for (int e = tid; e < WH * 8; e += 512) {
            const int k  = e >> 3;
            const int lp = e & 7;
            const float* qr = zbuf[lp];
            const float* qi = qr + 256;
            const int kq = (256 - k) & 255;
            const int sk = k ^ (k >> 5), sq = kq ^ (kq >> 5);
            const float2 P = make_float2(qr[sk], qi[sk]);
            const float2 Q = make_float2(qr[sq], qi[sq]);
            const __half2 a  = __floats2half2_rn(0.5f * (P.x + Q.x), 0.5f * (P.y - Q.y));
            const __half2 bb = __floats2half2_rn(0.5f * (P.y + Q.y), 0.5f * (Q.x - P.x));
            uint2 pk;
            pk.x = __builtin_bit_cast(unsigned, a);
            pk.y = __builtin_bit_cast(unsigned, bb);
            dst[(size_t)k * 128 + basePair + lp] = pk;
        }
        __syncthreads();                 // WAR: zbuf reused next iteration
    }
}

// 8 waves/block, XCD-pinned. DIAGNOSTIC: FFT+bin repeated REP_COL times on
// register-clobbered copies; gsum flush only on the last iteration.
__global__ __launch_bounds__(512)
void colfft_bin_t(const __half2* __restrict__ GT, float* __restrict__ gsum) {
    __shared__ float bins[VLEN];
    const int tid = threadIdx.x;
    const int t   = tid & 63;
    const int wid = tid >> 6;
    const int b   = blockIdx.x;        // 0..NIMG*17-1
    const int img = b & 63;            // XCD pin
    const int grp = b >> 6;            // 0..16
    const int j   = grp * 8 + wid;     // 0..135

    float2 z[4];
    const bool vj = j < WH;
    if (vj) {
        const __half2* col = GT + ((size_t)img * WH + j) * 256;
        #pragma unroll
        for (int r = 0; r < 4; ++r)
            z[r] = __half22float2(col[t + (r << 6)]);
    }

    for (int it = 0; it < REP_COL; ++it) {
        if (tid < VLEN) bins[tid] = 0.0f;
        __syncthreads();

        if (vj) {
            float2 zz[4];
            #pragma unroll
            for (int r = 0; r < 4; ++r) {
                zz[r] = z[r];
                asm volatile("" : "+v"(zz[r].x), "+v"(zz[r].y));  // defeat CSE
            }
            wfft256(zz, t);

            const int j2 = j * j;
            #pragma unroll
            for (int r = 0; r < 4; ++r) {
                const int n   = (int)(__brev((unsigned)(t + (r << 6))) >> 24);
                const int di  = (n < 128) ? n : n - 256;
                const int rad = isqrt_fast(di * di + j2);
                const float p = zz[r].x * zz[r].x + zz[r].y * zz[r].y + 1e-8f;
                atomicAdd(&bins[rad], 20.0f * __logf(p));
            }
        }
        __syncthreads();

        if (it == REP_COL - 1) {
            const int j0   = grp * 8;
            const int jmax = (j0 + 7 < WH) ? j0 + 7 : WH - 1;
            const int rmax = isqrt_fast(128 * 128 + jmax * jmax);
            float* gs = gsum + (size_t)img * VLEN;
            for (int v = j0 + tid; v <= rmax; v += 512)
                atomicAdd(&gs[v], bins[v]);
        }
    }
}

// 32 blocks, one per pred/target pair. DIAGNOSTIC: repeated REP_FIN times;
// out accumulation only on the last iteration.
__global__ __launch_bounds__(256)
void finish32(const float* __restrict__ gsum, float* __restrict__ out) {
    __shared__ int    scnt[VLEN];
    __shared__ float4 red4[256];
    __shared__ float  reds[256];
    const int tid = threadIdx.x;
    const int pr  = blockIdx.x;        // 0..31

    for (int it = 0; it < REP_FIN; ++it) {
        asm volatile("" ::: "memory");

        if (tid < VLEN) scnt[tid] = 0;
        __syncthreads();
        for (int e = tid; e < H * WH; e += 256) {
            const int k  = e / WH;
            const int j  = e - k * WH;
            const int di = (k < 128) ? k : k - 256;
            atomicAdd(&scnt[isqrt_fast(di * di + j * j)], 1);
        }
        __syncthreads();

        const bool val = tid < VLEN;
        float a = 0.0f, bv = 0.0f;
        float4 mm = make_float4(1e30f, -1e30f, 1e30f, -1e30f);
        if (val) {
            const float ic = 1.0f / (float)scnt[tid];
            a  = gsum[(size_t)pr * VLEN + tid] * ic;
            bv = gsum[(size_t)(pr + 32) * VLEN + tid] * ic;
            mm = make_float4(a, a, bv, bv);
        }
        red4[tid] = mm; __syncthreads();
        for (int off = 128; off > 0; off >>= 1) {
            if (tid < off) {
                const float4 o = red4[tid + off];
                red4[tid].x = fminf(red4[tid].x, o.x);
                red4[tid].y = fmaxf(red4[tid].y, o.y);
                red4[tid].z = fminf(red4[tid].z, o.z);
                red4[tid].w = fmaxf(red4[tid].w, o.w);
            }
            __syncthreads();
        }
        const float4 m = red4[0];
        const float inva = 1.0f / (m.y - m.x);
        const float invb = 1.0f / (m.w - m.z);
        const float d = val ? (a - m.x) * inva - (bv - m.z) * invb : 0.0f;
        reds[tid] = d * d; __syncthreads();
        for (int off = 128; off > 0; off >>= 1) {
            if (tid < off) reds[tid] += reds[tid + off];
            __syncthreads();
        }
        if (tid == 0 && it == REP_FIN - 1)
            atomicAdd(out, reds[0] * (1.0f / (float)(32 * VLEN)));
        __syncthreads();
    }
}

extern "C" void kernel_launch(void* const* d_in, const int* in_sizes, int n_in,
                              void* d_out, int out_size, void* d_ws, size_t ws_size,
                              hipStream_t stream) {
    const float* pred = (const float*)d_in[0];
    const float* targ = (const float*)d_in[1];
    float* out = (float*)d_out;

    char* ws = (char*)d_ws;
    uint2* GT = (uint2*)ws;                                      // NIMG*WH*128 uint2
    ws += (size_t)NIMG * WH * 128 * sizeof(uint2);
    float* gsum = (float*)ws;                                    // NIMG*VLEN floats

    rowfft_wave<<<NIMG * 16, 512, 0, stream>>>(pred, targ, GT, gsum, out);
    colfft_bin_t<<<NIMG * 17, 512, 0, stream>>>((const __half2*)GT, gsum);
    finish32<<<32, 256, 0, stream>>>(gsum, out);
}

// Round 23
// 35.268 us; speedup vs baseline: 9.3625x; 9.3625x over previous
//
#include <hip/hip_runtime.h>
#include <hip/hip_fp16.h>

#define H    256
#define W    256
#define WH   129            // W/2 + 1
#define VLEN 182            // max radial bin + 1
#define NIMG 64             // 32 pred + 32 target
#define ZSTR 516            // zbuf row stride in floats

typedef __attribute__((ext_vector_type(2))) unsigned uint2v;

// ---- compile-time radial-bin inverse counts -------------------------------
// counts[r] = #{(k,j): k in [0,256), j in [0,129), isqrt(di^2+j^2)==r},
// di = k<128 ? k : k-256. Built with ±di symmetry and an incremental isqrt
// (r is monotone in di for fixed j) => ~230K constexpr steps.
struct InvCounts { float v[VLEN]; };
constexpr InvCounts make_inv_counts() {
    InvCounts t{};
    int cnt[VLEN] = {};
    for (int j = 0; j < WH; ++j) {
        int r = j;                       // isqrt(0 + j*j) == j
        for (int di = 0; di <= 128; ++di) {
            const int s2 = di * di + j * j;
            while ((r + 1) * (r + 1) <= s2) ++r;
            cnt[r] += (di == 0 || di == 128) ? 1 : 2;   // di=-128 only; ±di else
        }
    }
    for (int v = 0; v < VLEN; ++v) t.v[v] = 1.0f / (float)cnt[v];
    return t;
}
constexpr InvCounts INVC = make_inv_counts();
// ---------------------------------------------------------------------------

__device__ __forceinline__ int isqrt_fast(int s2) {
    int r = (int)__builtin_amdgcn_sqrtf((float)s2);
    r -= (r * r > s2);
    r += ((r + 1) * (r + 1) <= s2);
    return r;
}

__device__ __forceinline__ float2 cmul(float2 a, float2 b) {
    return make_float2(a.x * b.x - a.y * b.y, a.x * b.y + a.y * b.x);
}

// Twiddle e^{-2*pi*i*frac} via raw v_sin/v_cos (argument in revolutions).
__device__ __forceinline__ float2 twid(float frac) {
    const float s = __builtin_amdgcn_sinf(frac);
    const float c = __builtin_amdgcn_cosf(frac);
    return make_float2(c, -s);
}

// 256-point DIF FFT held by one 64-lane wave; thread t owns positions
// i = t + 64r (r=0..3). On exit, position i holds X[bitrev8(i)].
__device__ __forceinline__ void wfft256(float2 z[4], int t) {
    // m=256
    {
        const float2 w0 = twid((float)t * (1.0f / 256.0f));
        const float2 w1 = make_float2(w0.y, -w0.x);    // w0 * (-i)
        float2 u0 = z[0], v0 = z[2], u1 = z[1], v1 = z[3];
        z[0] = make_float2(u0.x + v0.x, u0.y + v0.y);
        z[2] = cmul(make_float2(u0.x - v0.x, u0.y - v0.y), w0);
        z[1] = make_float2(u1.x + v1.x, u1.y + v1.y);
        z[3] = cmul(make_float2(u1.x - v1.x, u1.y - v1.y), w1);
    }
    // m=128
    {
        const float2 w = twid((float)t * (1.0f / 128.0f));
        float2 u0 = z[0], v0 = z[1], u1 = z[2], v1 = z[3];
        z[0] = make_float2(u0.x + v0.x, u0.y + v0.y);
        z[1] = cmul(make_float2(u0.x - v0.x, u0.y - v0.y), w);
        z[2] = make_float2(u1.x + v1.x, u1.y + v1.y);
        z[3] = cmul(make_float2(u1.x - v1.x, u1.y - v1.y), w);
    }
    // m=64: permlane32_swap (VALU crosslane)
    {
        const float2 w = twid((float)(t & 31) * (1.0f / 64.0f));
        const bool hi = (t & 32) != 0;
        #pragma unroll
        for (int r = 0; r < 4; ++r) {
            const uint2v px = __builtin_amdgcn_permlane32_swap(
                __builtin_bit_cast(unsigned, z[r].x),
                __builtin_bit_cast(unsigned, z[r].x), false, false);
            const uint2v py = __builtin_amdgcn_permlane32_swap(
                __builtin_bit_cast(unsigned, z[r].y),
                __builtin_bit_cast(unsigned, z[r].y), false, false);
            const float ox = __builtin_bit_cast(float, hi ? px[0] : px[1]);
            const float oy = __builtin_bit_cast(float, hi ? py[0] : py[1]);
            if (hi) z[r] = cmul(make_float2(ox - z[r].x, oy - z[r].y), w);
            else    z[r] = make_float2(z[r].x + ox, z[r].y + oy);
        }
    }
    // m=32: permlane16_swap
    {
        const float2 w = twid((float)(t & 15) * (1.0f / 32.0f));
        const bool hi = (t & 16) != 0;
        #pragma unroll
        for (int r = 0; r < 4; ++r) {
            const uint2v px = __builtin_amdgcn_permlane16_swap(
                __builtin_bit_cast(unsigned, z[r].x),
                __builtin_bit_cast(unsigned, z[r].x), false, false);
            const uint2v py = __builtin_amdgcn_permlane16_swap(
                __builtin_bit_cast(unsigned, z[r].y),
                __builtin_bit_cast(unsigned, z[r].y), false, false);
            const float ox = __builtin_bit_cast(float, hi ? px[0] : px[1]);
            const float oy = __builtin_bit_cast(float, hi ? py[0] : py[1]);
            if (hi) z[r] = cmul(make_float2(ox - z[r].x, oy - z[r].y), w);
            else    z[r] = make_float2(z[r].x + ox, z[r].y + oy);
        }
    }
    // m=16
    {
        const float2 w = twid((float)(t & 7) * (1.0f / 16.0f));
        const bool hi = (t & 8) != 0;
        #pragma unroll
        for (int r = 0; r < 4; ++r) {
            float2 o;
            o.x = __shfl_xor(z[r].x, 8, 64);
            o.y = __shfl_xor(z[r].y, 8, 64);
            if (hi) z[r] = cmul(make_float2(o.x - z[r].x, o.y - z[r].y), w);
            else    z[r] = make_float2(z[r].x + o.x, z[r].y + o.y);
        }
    }
    // m=8
    {
        const float2 w = twid((float)(t & 3) * (1.0f / 8.0f));
        const bool hi = (t & 4) != 0;
        #pragma unroll
        for (int r = 0; r < 4; ++r) {
            float2 o;
            o.x = __shfl_xor(z[r].x, 4, 64);
            o.y = __shfl_xor(z[r].y, 4, 64);
            if (hi) z[r] = cmul(make_float2(o.x - z[r].x, o.y - z[r].y), w);
            else    z[r] = make_float2(z[r].x + o.x, z[r].y + o.y);
        }
    }
    // m=4: w = 1 (t even) or -i (t odd)
    {
        const bool hi  = (t & 2) != 0;
        const bool odd = (t & 1) != 0;
        #pragma unroll
        for (int r = 0; r < 4; ++r) {
            float2 o;
            o.x = __shfl_xor(z[r].x, 2, 64);
            o.y = __shfl_xor(z[r].y, 2, 64);
            float2 d = hi ? make_float2(o.x - z[r].x, o.y - z[r].y)
                          : make_float2(z[r].x + o.x, z[r].y + o.y);
            if (hi && odd) d = make_float2(d.y, -d.x);   // * (-i)
            z[r] = d;
        }
    }
    // m=2
    {
        const bool hi = (t & 1) != 0;
        #pragma unroll
        for (int r = 0; r < 4; ++r) {
            float2 o;
            o.x = __shfl_xor(z[r].x, 1, 64);
            o.y = __shfl_xor(z[r].y, 1, 64);
            z[r] = hi ? make_float2(o.x - z[r].x, o.y - z[r].y)
                      : make_float2(z[r].x + o.x, z[r].y + o.y);
        }
    }
}

// 8 waves/block. XCD-pinned block mapping: img = b & 63. Each wave: coalesced
// luma loads for a packed row-pair, wave FFT, per-wave LDS stash; block-
// cooperative unpack + coalesced transposed store.
__global__ __launch_bounds__(512)
void rowfft_wave(const float* __restrict__ pred, const float* __restrict__ targ,
                 uint2* __restrict__ GT /* [NIMG][WH][128] uint2 = row-pair */,
                 float* __restrict__ gsum /* [NIMG][VLEN] */,
                 float* __restrict__ out) {
    __shared__ float zbuf[8][ZSTR];    // per wave: re[256] + im[256], swizzled
    const int tid  = threadIdx.x;
    const int t    = tid & 63;
    const int wid  = tid >> 6;         // 0..7
    const int b    = blockIdx.x;       // 0..1023
    const int img  = b & 63;           // XCD pin: b%8 == img%8
    const int k16  = b >> 6;           // 0..15 (16 blocks per image)
    const int pair = (k16 << 3) | wid;
    const int rowA = pair * 2;

    if (k16 == 0) {
        if (tid < VLEN) gsum[img * VLEN + tid] = 0.0f;
    }
    if (b == 0 && tid == 0) out[0] = 0.0f;

    const float* src  = (img < 32) ? pred : targ;
    const float* base = src + (size_t)(img & 31) * (3 * H * W) + (size_t)rowA * W;

    float2 z[4];
    #pragma unroll
    for (int r = 0; r < 4; ++r) {
        const int n = t + (r << 6);
        const float aR = __builtin_nontemporal_load(base + n);
        const float aG = __builtin_nontemporal_load(base + H * W + n);
        const float aB = __builtin_nontemporal_load(base + 2 * H * W + n);
        const float bR = __builtin_nontemporal_load(base + W + n);
        const float bG = __builtin_nontemporal_load(base + H * W + W + n);
        const float bB = __builtin_nontemporal_load(base + 2 * H * W + W + n);
        z[r] = make_float2(0.299f * aR + 0.587f * aG + 0.114f * aB,
                           0.299f * bR + 0.587f * bG + 0.114f * bB);
    }

    wfft256(z, t);

    float* zr = zbuf[wid];
    float* zi = zr + 256;
    #pragma unroll
    for (int r = 0; r < 4; ++r) {
        const int x  = (int)(__brev((unsigned)(t + (r << 6))) >> 24);
        const int sx = x ^ (x >> 5);
        zr[sx] = z[r].x; zi[sx] = z[r].y;
    }
    __syncthreads();                   // all 8 waves' spectra visible

    // Ga[k] = (Z[k]+conj(Z[-k]))/2, Gb[k] = -i(Z[k]-conj(Z[-k]))/2
    uint2* dst = GT + (size_t)img * WH * 128;
    const int basePair = k16 << 3;
    for (int e = tid; e < WH * 8; e += 512) {
        const int k  = e >> 3;
        const int lp = e & 7;
        const float* qr = zbuf[lp];
        const float* qi = qr + 256;
        const int kq = (256 - k) & 255;
        const int sk = k ^ (k >> 5), sq = kq ^ (kq >> 5);
        const float2 P = make_float2(qr[sk], qi[sk]);
        const float2 Q = make_float2(qr[sq], qi[sq]);
        const __half2 a  = __floats2half2_rn(0.5f * (P.x + Q.x), 0.5f * (P.y - Q.y));
        const __half2 bb = __floats2half2_rn(0.5f * (P.y + Q.y), 0.5f * (Q.x - P.x));
        uint2 pk;
        pk.x = __builtin_bit_cast(unsigned, a);
        pk.y = __builtin_bit_cast(unsigned, bb);
        dst[(size_t)k * 128 + basePair + lp] = pk;
    }
}

// 8 waves/block, one column-FFT per wave. XCD-pinned: img = b & 63; GT[img]
// loads hit the local XCD L2. Loads issued BEFORE the bins-zero barrier.
__global__ __launch_bounds__(512)
void colfft_bin_t(const __half2* __restrict__ GT, float* __restrict__ gsum) {
    __shared__ float bins[VLEN];
    const int tid = threadIdx.x;
    const int t   = tid & 63;
    const int wid = tid >> 6;          // 0..7
    const int b   = blockIdx.x;        // 0..NIMG*17-1
    const int img = b & 63;            // XCD pin
    const int grp = b >> 6;            // 0..16
    const int j   = grp * 8 + wid;     // 0..135

    float2 z[4];
    const bool vj = j < WH;
    if (vj) {
        const __half2* col = GT + ((size_t)img * WH + j) * 256;
        #pragma unroll
        for (int r = 0; r < 4; ++r)
            z[r] = __half22float2(col[t + (r << 6)]);
    }

    if (tid < VLEN) bins[tid] = 0.0f;
    __syncthreads();

    if (vj) {
        wfft256(z, t);

        const int j2 = j * j;
        #pragma unroll
        for (int r = 0; r < 4; ++r) {
            const int n   = (int)(__brev((unsigned)(t + (r << 6))) >> 24);
            const int di  = (n < 128) ? n : n - 256;
            const int rad = isqrt_fast(di * di + j2);
            const float p = z[r].x * z[r].x + z[r].y * z[r].y + 1e-8f;
            atomicAdd(&bins[rad], 20.0f * __logf(p));
        }
    }
    __syncthreads();

    const int j0   = grp * 8;
    const int jmax = (j0 + 7 < WH) ? j0 + 7 : WH - 1;
    const int rmax = isqrt_fast(128 * 128 + jmax * jmax);
    float* gs = gsum + (size_t)img * VLEN;
    for (int v = j0 + tid; v <= rmax; v += 512)
        atomicAdd(&gs[v], bins[v]);
}

// 32 blocks, one per pred/target pair. Counts come from the compile-time
// table (no atomics, no e-loop). Wave-shuffle reductions, 2 barriers total.
__global__ __launch_bounds__(256)
void finish32(const float* __restrict__ gsum, float* __restrict__ out) {
    __shared__ float2 wa[4], wb[4];
    __shared__ float  wsse[4];
    const int tid = threadIdx.x;
    const int t   = tid & 63;
    const int wv  = tid >> 6;          // 0..3
    const int pr  = blockIdx.x;        // 0..31
    const bool val = tid < VLEN;

    float a = 0.0f, b = 0.0f;
    float mna = 1e30f, mxa = -1e30f, mnb = 1e30f, mxb = -1e30f;
    if (val) {
        const float ic = INVC.v[tid];
        a = gsum[(size_t)pr * VLEN + tid] * ic;
        b = gsum[(size_t)(pr + 32) * VLEN + tid] * ic;
        mna = a; mxa = a; mnb = b; mxb = b;
    }
    #pragma unroll
    for (int m = 32; m >= 1; m >>= 1) {
        mna = fminf(mna, __shfl_xor(mna, m, 64));
        mxa = fmaxf(mxa, __shfl_xor(mxa, m, 64));
        mnb = fminf(mnb, __shfl_xor(mnb, m, 64));
        mxb = fmaxf(mxb, __shfl_xor(mxb, m, 64));
    }
    if (t == 0) { wa[wv] = make_float2(mna, mxa); wb[wv] = make_float2(mnb, mxb); }
    __syncthreads();

    float2 ca = wa[0], cb = wb[0];
    #pragma unroll
    for (int i = 1; i < 4; ++i) {
        ca.x = fminf(ca.x, wa[i].x); ca.y = fmaxf(ca.y, wa[i].y);
        cb.x = fminf(cb.x, wb[i].x); cb.y = fmaxf(cb.y, wb[i].y);
    }
    const float inva = 1.0f / (ca.y - ca.x);
    const float invb = 1.0f / (cb.y - cb.x);
    const float d = val ? (a - ca.x) * inva - (b - cb.x) * invb : 0.0f;
    float sse = d * d;
    #pragma unroll
    for (int m = 32; m >= 1; m >>= 1) sse += __shfl_xor(sse, m, 64);
    if (t == 0) wsse[wv] = sse;
    __syncthreads();
    if (tid == 0)
        atomicAdd(out, (wsse[0] + wsse[1] + wsse[2] + wsse[3]) *
                       (1.0f / (float)(32 * VLEN)));
}

extern "C" void kernel_launch(void* const* d_in, const int* in_sizes, int n_in,
                              void* d_out, int out_size, void* d_ws, size_t ws_size,
                              hipStream_t stream) {
    const float* pred = (const float*)d_in[0];
    const float* targ = (const float*)d_in[1];
    float* out = (float*)d_out;

    char* ws = (char*)d_ws;
    uint2* GT = (uint2*)ws;                                      // NIMG*WH*128 uint2
    ws += (size_t)NIMG * WH * 128 * sizeof(uint2);
    float* gsum = (float*)ws;                                    // NIMG*VLEN floats

    rowfft_wave<<<NIMG * 16, 512, 0, stream>>>(pred, targ, GT, gsum, out);
    colfft_bin_t<<<NIMG * 17, 512, 0, stream>>>((const __half2*)GT, gsum);
    finish32<<<32, 256, 0, stream>>>(gsum, out);
}